// Round 1
// baseline (1029.385 us; speedup 1.0000x reference)
//
#include <hip/hip_runtime.h>
#include <cstdint>

// ---------------------------------------------------------------------------
// GCN pipeline:
//  deg/dinv -> CSR build (cnt/scan/scatter) -> GEMM1 -> AGG1(+b1,relu)
//  -> GEMM2 -> AGG2(+b2,relu) -> mean-pool per graph -> fused head
// ---------------------------------------------------------------------------

__global__ void k_init_small(int* gstart, int* gcnt, int G) {
    int g = blockIdx.x * blockDim.x + threadIdx.x;
    if (g < G) { gstart[g] = 0x7fffffff; gcnt[g] = 0; }
}

__global__ void k_init_nodes(const int* __restrict__ batch, float* deg, int* cnt,
                             int* fill, int* gstart, int* gcnt, int N) {
    int i = blockIdx.x * blockDim.x + threadIdx.x;
    if (i >= N) return;
    deg[i] = 1.0f;   // self-loop weight
    cnt[i] = 0;
    fill[i] = 0;
    int b = batch[i];
    if (i == 0 || batch[i - 1] != b) gstart[b] = i;  // batch sorted -> unique writer
    atomicAdd(&gcnt[b], 1);
}

__global__ void k_edge1(const int* __restrict__ dst, const float* __restrict__ ew,
                        float* deg, int* cnt, int E) {
    int e = blockIdx.x * blockDim.x + threadIdx.x;
    if (e >= E) return;
    int d = dst[e];
    atomicAdd(&deg[d], ew[e]);
    atomicAdd(&cnt[d], 1);
}

__global__ void k_dinv(const float* __restrict__ deg, float* dinv, int N) {
    int i = blockIdx.x * blockDim.x + threadIdx.x;
    if (i < N) dinv[i] = rsqrtf(deg[i]);  // deg >= 1 always (self loop)
}

// single-block exclusive scan of cnt[N] -> rowptr[N+1]
__global__ void k_scan(const int* __restrict__ cnt, int* __restrict__ rowptr, int N) {
    __shared__ int sm[1024];
    int tid = threadIdx.x;
    int per = (N + 1023) >> 10;
    int b = tid * per, e = min(b + per, N);
    int s = 0;
    for (int i = b; i < e; ++i) s += cnt[i];
    sm[tid] = s;
    __syncthreads();
    for (int d = 1; d < 1024; d <<= 1) {
        int t = (tid >= d) ? sm[tid - d] : 0;
        __syncthreads();
        sm[tid] += t;
        __syncthreads();
    }
    int off = sm[tid] - s;  // exclusive prefix
    for (int i = b; i < e; ++i) { rowptr[i] = off; off += cnt[i]; }
    if (tid == 1023) rowptr[N] = off;  // tid 1023's range is empty (b > N), off == total
}

__global__ void k_edge2(const int* __restrict__ src, const int* __restrict__ dst,
                        const float* __restrict__ ew, const float* __restrict__ dinv,
                        const int* __restrict__ rowptr, int* fill,
                        int* __restrict__ colb, float* __restrict__ valb, int E) {
    int e = blockIdx.x * blockDim.x + threadIdx.x;
    if (e >= E) return;
    int s = src[e], d = dst[e];
    int pos = rowptr[d] + atomicAdd(&fill[d], 1);
    colb[pos] = s;
    valb[pos] = dinv[s] * ew[e] * dinv[d];
}

// Y[M,128] = X[M,128] @ W[128,128]   (f32, W staged in LDS as k-quads)
// block: 256 thr = 4 waves; wave w -> cols [32w,32w+32); lane -> one row.
__global__ __launch_bounds__(256) void k_gemm(const float* __restrict__ X,
                                              const float* __restrict__ W,
                                              float* __restrict__ Y, int M) {
    __shared__ float4 wq[32][128];  // wq[k4][c] = (W[4k4..4k4+3][c]) ; 64 KB
    int tid = threadIdx.x;
    for (int idx = tid; idx < 128 * 128; idx += 256) {
        int k = idx >> 7, c = idx & 127;
        ((float*)&wq[k >> 2][c])[k & 3] = W[idx];
    }
    __syncthreads();
    int wid = tid >> 6, lane = tid & 63;
    int row = blockIdx.x * 64 + lane;
    int c0 = wid * 32;
    if (row >= M) return;
    float acc[32];
#pragma unroll
    for (int c = 0; c < 32; ++c) acc[c] = 0.f;
    const float4* __restrict__ xrow = reinterpret_cast<const float4*>(X + (size_t)row * 128);
#pragma unroll 4
    for (int k4 = 0; k4 < 32; ++k4) {
        float4 xv = xrow[k4];
#pragma unroll
        for (int c = 0; c < 32; ++c) {
            float4 wv = wq[k4][c0 + c];
            acc[c] = fmaf(xv.x, wv.x, acc[c]);
            acc[c] = fmaf(xv.y, wv.y, acc[c]);
            acc[c] = fmaf(xv.z, wv.z, acc[c]);
            acc[c] = fmaf(xv.w, wv.w, acc[c]);
        }
    }
    float4* yrow = reinterpret_cast<float4*>(Y + (size_t)row * 128 + c0);
#pragma unroll
    for (int q = 0; q < 8; ++q)
        yrow[q] = make_float4(acc[4 * q], acc[4 * q + 1], acc[4 * q + 2], acc[4 * q + 3]);
}

// Out[d] = relu( sum_e val[e]*Hin[col[e]] + dinv[d]^2*Hin[d] + bias )
// one wave per node; lane holds 2 features (float2).
__global__ __launch_bounds__(256) void k_agg(const float* __restrict__ Hin,
                                             const int* __restrict__ rowptr,
                                             const int* __restrict__ colb,
                                             const float* __restrict__ valb,
                                             const float* __restrict__ dinv,
                                             const float* __restrict__ bias,
                                             float* __restrict__ Out, int N) {
    int lane = threadIdx.x & 63;
    int node = blockIdx.x * 4 + (threadIdx.x >> 6);
    if (node >= N) return;
    const float2* __restrict__ H2 = reinterpret_cast<const float2*>(Hin);
    int beg = rowptr[node], end = rowptr[node + 1];
    float di = dinv[node];
    float2 hs = H2[(size_t)node * 64 + lane];
    float sn = di * di;
    float a0 = sn * hs.x, a1 = sn * hs.y;
    int n = end - beg;
    for (int base = 0; base < n; base += 64) {
        int m = min(64, n - base);
        int cl = 0; float vl = 0.f;
        if (base + lane < n) {
            int gi = beg + base + lane;
            cl = colb[gi];
            vl = valb[gi];
        }
        for (int j0 = 0; j0 < m; j0 += 4) {
#pragma unroll
            for (int jj = 0; jj < 4; ++jj) {
                int j = j0 + jj;
                if (j < m) {
                    int sIdx = __shfl(cl, j);
                    float v = __shfl(vl, j);
                    float2 h = H2[(size_t)sIdx * 64 + lane];
                    a0 = fmaf(v, h.x, a0);
                    a1 = fmaf(v, h.y, a1);
                }
            }
        }
    }
    float2 bv = reinterpret_cast<const float2*>(bias)[lane];
    a0 = fmaxf(a0 + bv.x, 0.f);
    a1 = fmaxf(a1 + bv.y, 0.f);
    reinterpret_cast<float2*>(Out)[(size_t)node * 64 + lane] = make_float2(a0, a1);
}

// mean pool: batch sorted -> graph g is rows [gstart[g], gstart[g]+gcnt[g])
__global__ __launch_bounds__(256) void k_pool(const float* __restrict__ Hfin,
                                              const int* __restrict__ gstart,
                                              const int* __restrict__ gcnt,
                                              float* __restrict__ gmean) {
    int g = blockIdx.x;
    int tid = threadIdx.x;
    int c = tid & 127, half = tid >> 7;
    __shared__ float red[256];
    int cntg = gcnt[g];
    int b = gstart[g];
    float s = 0.f;
    for (int i = half; i < cntg; i += 2) s += Hfin[(size_t)(b + i) * 128 + c];
    red[tid] = s;
    __syncthreads();
    if (half == 0) {
        float tot = red[c] + red[c + 128];
        gmean[g * 128 + c] = tot / fmaxf((float)cntg, 1.f);
    }
}

// head: md = relu(metadata[first%G] @ Wm + bm); out = [pooled, md] @ Wf + bf
__global__ __launch_bounds__(128) void k_final(const float* __restrict__ gmean,
                                               const int* __restrict__ gstart,
                                               const float* __restrict__ meta,
                                               const float* __restrict__ Wm,
                                               const float* __restrict__ bm,
                                               const float* __restrict__ Wf,
                                               const float* __restrict__ bf,
                                               float* __restrict__ out, int G) {
    int g = blockIdx.x;
    int c = threadIdx.x;  // 128 threads
    __shared__ float red[128];
    float pooled = gmean[g * 128 + c];
    int fn = gstart[g];          // INT_MAX for empty graph (matches segment_min identity)
    int idx = fn % G;            // metadata.shape[0] == G
    float m = bm[c];
#pragma unroll
    for (int k = 0; k < 30; ++k) m = fmaf(meta[idx * 30 + k], Wm[k * 128 + c], m);
    m = fmaxf(m, 0.f);
    float part = pooled * Wf[c] + m * Wf[128 + c];
    red[c] = part;
    __syncthreads();
    for (int st = 64; st > 0; st >>= 1) {
        if (c < st) red[c] += red[c + st];
        __syncthreads();
    }
    if (c == 0) out[g] = red[0] + bf[0];
}

extern "C" void kernel_launch(void* const* d_in, const int* in_sizes, int n_in,
                              void* d_out, int out_size, void* d_ws, size_t ws_size,
                              hipStream_t stream) {
    const float* x     = (const float*)d_in[0];
    const int*   ei    = (const int*)d_in[1];
    const float* ew    = (const float*)d_in[2];
    const int*   batch = (const int*)d_in[3];
    const float* meta  = (const float*)d_in[4];
    const float* W1    = (const float*)d_in[5];
    const float* b1    = (const float*)d_in[6];
    const float* W2    = (const float*)d_in[7];
    const float* b2    = (const float*)d_in[8];
    const float* Wm    = (const float*)d_in[9];
    const float* bm    = (const float*)d_in[10];
    const float* Wf    = (const float*)d_in[11];
    const float* bf    = (const float*)d_in[12];

    int N = in_sizes[0] / 128;
    int E = in_sizes[2];
    int G = in_sizes[4] / 30;
    const int* srcp = ei;
    const int* dstp = ei + E;

    char* p = (char*)d_ws;
    auto alloc = [&](size_t bytes) -> void* {
        void* r = p;
        p += (bytes + 255) & ~(size_t)255;
        return r;
    };
    float* deg    = (float*)alloc((size_t)N * 4);
    float* dinv   = (float*)alloc((size_t)N * 4);
    int*   cnt    = (int*)alloc((size_t)N * 4);
    int*   fill   = (int*)alloc((size_t)N * 4);
    int*   rowptr = (int*)alloc((size_t)(N + 1) * 4);
    int*   colb   = (int*)alloc((size_t)E * 4);
    float* valb   = (float*)alloc((size_t)E * 4);
    float* bufA   = (float*)alloc((size_t)N * 128 * 4);
    float* bufB   = (float*)alloc((size_t)N * 128 * 4);
    float* gmean  = (float*)alloc((size_t)G * 128 * 4);
    int*   gstart = (int*)alloc((size_t)G * 4);
    int*   gcnt   = (int*)alloc((size_t)G * 4);

    k_init_small<<<(G + 255) / 256, 256, 0, stream>>>(gstart, gcnt, G);
    k_init_nodes<<<(N + 255) / 256, 256, 0, stream>>>(batch, deg, cnt, fill, gstart, gcnt, N);
    k_edge1<<<(E + 255) / 256, 256, 0, stream>>>(dstp, ew, deg, cnt, E);
    k_dinv<<<(N + 255) / 256, 256, 0, stream>>>(deg, dinv, N);
    k_scan<<<1, 1024, 0, stream>>>(cnt, rowptr, N);
    k_edge2<<<(E + 255) / 256, 256, 0, stream>>>(srcp, dstp, ew, dinv, rowptr, fill, colb, valb, E);

    k_gemm<<<(N + 63) / 64, 256, 0, stream>>>(x, W1, bufA, N);
    k_agg<<<(N + 3) / 4, 256, 0, stream>>>(bufA, rowptr, colb, valb, dinv, b1, bufB, N);
    k_gemm<<<(N + 63) / 64, 256, 0, stream>>>(bufB, W2, bufA, N);
    k_agg<<<(N + 3) / 4, 256, 0, stream>>>(bufA, rowptr, colb, valb, dinv, b2, bufB, N);

    k_pool<<<G, 256, 0, stream>>>(bufB, gstart, gcnt, gmean);
    k_final<<<G, 128, 0, stream>>>(gmean, gstart, meta, Wm, bm, Wf, bf, (float*)d_out, G);
}

// Round 2
// 733.688 us; speedup vs baseline: 1.4030x; 1.4030x over previous
//
#include <hip/hip_runtime.h>
#include <cstdint>

// ---------------------------------------------------------------------------
// GCN pipeline:
//  deg/dinv -> CSR build (cnt / 3-phase scan / scatter) -> GEMM1 -> AGG1
//  -> GEMM2 -> AGG2 -> mean-pool per graph -> fused head
// ---------------------------------------------------------------------------

#define SCAN_CHUNK 512  // elements per scan block (multiple of 256)

__global__ void k_init_small(int* gstart, int* gcnt, int G) {
    int g = blockIdx.x * blockDim.x + threadIdx.x;
    if (g < G) { gstart[g] = 0x7fffffff; gcnt[g] = 0; }
}

__global__ void k_init_nodes(const int* __restrict__ batch, float* deg, int* cnt,
                             int* fill, int* gstart, int* gcnt, int N) {
    int i = blockIdx.x * blockDim.x + threadIdx.x;
    if (i >= N) return;
    deg[i] = 1.0f;   // self-loop weight
    cnt[i] = 0;
    fill[i] = 0;
    int b = batch[i];
    if (i == 0 || batch[i - 1] != b) gstart[b] = i;  // batch sorted -> unique writer
    atomicAdd(&gcnt[b], 1);
}

__global__ void k_edge1(const int* __restrict__ dst, const float* __restrict__ ew,
                        float* deg, int* cnt, int E) {
    int e = blockIdx.x * blockDim.x + threadIdx.x;
    if (e >= E) return;
    int d = dst[e];
    atomicAdd(&deg[d], ew[e]);
    atomicAdd(&cnt[d], 1);
}

__global__ void k_dinv(const float* __restrict__ deg, float* dinv, int N) {
    int i = blockIdx.x * blockDim.x + threadIdx.x;
    if (i < N) dinv[i] = rsqrtf(deg[i]);  // deg >= 1 always (self loop)
}

// ---- 3-phase exclusive scan of cnt[N] -> rowptr[N+1] ----------------------
__global__ __launch_bounds__(256) void k_scan_a(const int* __restrict__ cnt,
                                                int* __restrict__ bsum, int N) {
    __shared__ int sm[256];
    int base = blockIdx.x * SCAN_CHUNK;
    int end = min(base + SCAN_CHUNK, N);
    int s = 0;
    for (int i = base + threadIdx.x; i < end; i += 256) s += cnt[i];
    sm[threadIdx.x] = s;
    __syncthreads();
    for (int d = 128; d > 0; d >>= 1) {
        if (threadIdx.x < d) sm[threadIdx.x] += sm[threadIdx.x + d];
        __syncthreads();
    }
    if (threadIdx.x == 0) bsum[blockIdx.x] = sm[0];
}

__global__ __launch_bounds__(1024) void k_scan_b(const int* __restrict__ bsum,
                                                 int* __restrict__ boff,
                                                 int* __restrict__ rowptr,
                                                 int NB, int N) {
    __shared__ int sm[1024];
    int tid = threadIdx.x;
    int v = (tid < NB) ? bsum[tid] : 0;
    sm[tid] = v;
    __syncthreads();
    for (int d = 1; d < 1024; d <<= 1) {
        int t = (tid >= d) ? sm[tid - d] : 0;
        __syncthreads();
        sm[tid] += t;
        __syncthreads();
    }
    if (tid < NB) boff[tid] = sm[tid] - v;   // exclusive
    if (tid == NB - 1) rowptr[N] = sm[tid];  // total
}

__global__ __launch_bounds__(256) void k_scan_c(const int* __restrict__ cnt,
                                                const int* __restrict__ boff,
                                                int* __restrict__ rowptr, int N) {
    __shared__ int sm[256];
    int base = blockIdx.x * SCAN_CHUNK;
    int end = min(base + SCAN_CHUNK, N);
    int running = boff[blockIdx.x];
    for (int t0 = base; t0 < end; t0 += 256) {
        int i = t0 + threadIdx.x;
        int v = (i < end) ? cnt[i] : 0;
        sm[threadIdx.x] = v;
        __syncthreads();
        for (int d = 1; d < 256; d <<= 1) {
            int t = (threadIdx.x >= d) ? sm[threadIdx.x - d] : 0;
            __syncthreads();
            sm[threadIdx.x] += t;
            __syncthreads();
        }
        if (i < end) rowptr[i] = running + sm[threadIdx.x] - v;
        running += sm[255];
        __syncthreads();
    }
}
// ---------------------------------------------------------------------------

__global__ void k_edge2(const int* __restrict__ src, const int* __restrict__ dst,
                        const float* __restrict__ ew, const float* __restrict__ dinv,
                        const int* __restrict__ rowptr, int* fill,
                        int* __restrict__ colb, float* __restrict__ valb, int E) {
    int e = blockIdx.x * blockDim.x + threadIdx.x;
    if (e >= E) return;
    int s = src[e], d = dst[e];
    int pos = rowptr[d] + atomicAdd(&fill[d], 1);
    colb[pos] = s;
    valb[pos] = dinv[s] * ew[e] * dinv[d];
}

// Y[M,128] = X[M,128] @ W[128,128]   (f32; W via wave-uniform scalar loads)
// block: 256 thr = 4 waves; wave w -> cols [32w,32w+32); lane -> one row.
__global__ __launch_bounds__(256) void k_gemm(const float* __restrict__ X,
                                              const float* __restrict__ W,
                                              float* __restrict__ Y, int M) {
    int tid = threadIdx.x;
    int wid = tid >> 6, lane = tid & 63;
    int row = blockIdx.x * 64 + lane;
    int c0 = __builtin_amdgcn_readfirstlane(wid * 32);  // wave-uniform col base
    if (row >= M) return;
    float acc[32];
#pragma unroll
    for (int c = 0; c < 32; ++c) acc[c] = 0.f;
    const float4* __restrict__ xrow = reinterpret_cast<const float4*>(X + (size_t)row * 128);
#pragma unroll 8
    for (int k4 = 0; k4 < 32; ++k4) {
        float4 xv = xrow[k4];
#pragma unroll
        for (int j = 0; j < 4; ++j) {
            float xk = (j == 0) ? xv.x : (j == 1) ? xv.y : (j == 2) ? xv.z : xv.w;
            const float* __restrict__ wrow = W + (size_t)(k4 * 4 + j) * 128 + c0;
#pragma unroll
            for (int c = 0; c < 32; ++c) acc[c] = fmaf(xk, wrow[c], acc[c]);
        }
    }
    float4* yrow = reinterpret_cast<float4*>(Y + (size_t)row * 128 + c0);
#pragma unroll
    for (int q = 0; q < 8; ++q)
        yrow[q] = make_float4(acc[4 * q], acc[4 * q + 1], acc[4 * q + 2], acc[4 * q + 3]);
}

// Out[d] = relu( sum_e val[e]*Hin[col[e]] + dinv[d]^2*Hin[d] + bias )
// one wave per node; lane holds 2 features (float2).
__global__ __launch_bounds__(256) void k_agg(const float* __restrict__ Hin,
                                             const int* __restrict__ rowptr,
                                             const int* __restrict__ colb,
                                             const float* __restrict__ valb,
                                             const float* __restrict__ dinv,
                                             const float* __restrict__ bias,
                                             float* __restrict__ Out, int N) {
    int lane = threadIdx.x & 63;
    int node = blockIdx.x * 4 + (threadIdx.x >> 6);
    if (node >= N) return;
    const float2* __restrict__ H2 = reinterpret_cast<const float2*>(Hin);
    int beg = rowptr[node], end = rowptr[node + 1];
    float di = dinv[node];
    float2 hs = H2[(size_t)node * 64 + lane];
    float sn = di * di;
    float a0 = sn * hs.x, a1 = sn * hs.y;
    int n = end - beg;
    for (int base = 0; base < n; base += 64) {
        int m = min(64, n - base);
        int cl = 0; float vl = 0.f;
        if (base + lane < n) {
            int gi = beg + base + lane;
            cl = colb[gi];
            vl = valb[gi];
        }
        for (int j0 = 0; j0 < m; j0 += 4) {
#pragma unroll
            for (int jj = 0; jj < 4; ++jj) {
                int j = j0 + jj;
                if (j < m) {
                    int sIdx = __shfl(cl, j);
                    float v = __shfl(vl, j);
                    float2 h = H2[(size_t)sIdx * 64 + lane];
                    a0 = fmaf(v, h.x, a0);
                    a1 = fmaf(v, h.y, a1);
                }
            }
        }
    }
    float2 bv = reinterpret_cast<const float2*>(bias)[lane];
    a0 = fmaxf(a0 + bv.x, 0.f);
    a1 = fmaxf(a1 + bv.y, 0.f);
    reinterpret_cast<float2*>(Out)[(size_t)node * 64 + lane] = make_float2(a0, a1);
}

// mean pool: batch sorted -> graph g is rows [gstart[g], gstart[g]+gcnt[g])
__global__ __launch_bounds__(256) void k_pool(const float* __restrict__ Hfin,
                                              const int* __restrict__ gstart,
                                              const int* __restrict__ gcnt,
                                              float* __restrict__ gmean) {
    int g = blockIdx.x;
    int tid = threadIdx.x;
    int c = tid & 127, half = tid >> 7;
    __shared__ float red[256];
    int cntg = gcnt[g];
    int b = gstart[g];
    float s = 0.f;
    for (int i = half; i < cntg; i += 2) s += Hfin[(size_t)(b + i) * 128 + c];
    red[tid] = s;
    __syncthreads();
    if (half == 0) {
        float tot = red[c] + red[c + 128];
        gmean[g * 128 + c] = tot / fmaxf((float)cntg, 1.f);
    }
}

// head: md = relu(metadata[first%G] @ Wm + bm); out = [pooled, md] @ Wf + bf
__global__ __launch_bounds__(128) void k_final(const float* __restrict__ gmean,
                                               const int* __restrict__ gstart,
                                               const float* __restrict__ meta,
                                               const float* __restrict__ Wm,
                                               const float* __restrict__ bm,
                                               const float* __restrict__ Wf,
                                               const float* __restrict__ bf,
                                               float* __restrict__ out, int G) {
    int g = blockIdx.x;
    int c = threadIdx.x;  // 128 threads
    __shared__ float red[128];
    float pooled = gmean[g * 128 + c];
    int fn = gstart[g];          // INT_MAX for empty graph (matches segment_min identity)
    int idx = fn % G;            // metadata.shape[0] == G
    float m = bm[c];
#pragma unroll
    for (int k = 0; k < 30; ++k) m = fmaf(meta[idx * 30 + k], Wm[k * 128 + c], m);
    m = fmaxf(m, 0.f);
    float part = pooled * Wf[c] + m * Wf[128 + c];
    red[c] = part;
    __syncthreads();
    for (int st = 64; st > 0; st >>= 1) {
        if (c < st) red[c] += red[c + st];
        __syncthreads();
    }
    if (c == 0) out[g] = red[0] + bf[0];
}

extern "C" void kernel_launch(void* const* d_in, const int* in_sizes, int n_in,
                              void* d_out, int out_size, void* d_ws, size_t ws_size,
                              hipStream_t stream) {
    const float* x     = (const float*)d_in[0];
    const int*   ei    = (const int*)d_in[1];
    const float* ew    = (const float*)d_in[2];
    const int*   batch = (const int*)d_in[3];
    const float* meta  = (const float*)d_in[4];
    const float* W1    = (const float*)d_in[5];
    const float* b1    = (const float*)d_in[6];
    const float* W2    = (const float*)d_in[7];
    const float* b2    = (const float*)d_in[8];
    const float* Wm    = (const float*)d_in[9];
    const float* bm    = (const float*)d_in[10];
    const float* Wf    = (const float*)d_in[11];
    const float* bf    = (const float*)d_in[12];

    int N = in_sizes[0] / 128;
    int E = in_sizes[2];
    int G = in_sizes[4] / 30;
    const int* srcp = ei;
    const int* dstp = ei + E;

    char* p = (char*)d_ws;
    auto alloc = [&](size_t bytes) -> void* {
        void* r = p;
        p += (bytes + 255) & ~(size_t)255;
        return r;
    };
    float* deg    = (float*)alloc((size_t)N * 4);
    float* dinv   = (float*)alloc((size_t)N * 4);
    int*   cnt    = (int*)alloc((size_t)N * 4);
    int*   fill   = (int*)alloc((size_t)N * 4);
    int*   rowptr = (int*)alloc((size_t)(N + 1) * 4);
    int*   colb   = (int*)alloc((size_t)E * 4);
    float* valb   = (float*)alloc((size_t)E * 4);
    float* bufA   = (float*)alloc((size_t)N * 128 * 4);
    float* bufB   = (float*)alloc((size_t)N * 128 * 4);
    float* gmean  = (float*)alloc((size_t)G * 128 * 4);
    int*   gstart = (int*)alloc((size_t)G * 4);
    int*   gcnt   = (int*)alloc((size_t)G * 4);
    int NB = (N + SCAN_CHUNK - 1) / SCAN_CHUNK;
    int*   bsum   = (int*)alloc((size_t)NB * 4);
    int*   boff   = (int*)alloc((size_t)NB * 4);

    k_init_small<<<(G + 255) / 256, 256, 0, stream>>>(gstart, gcnt, G);
    k_init_nodes<<<(N + 255) / 256, 256, 0, stream>>>(batch, deg, cnt, fill, gstart, gcnt, N);
    k_edge1<<<(E + 255) / 256, 256, 0, stream>>>(dstp, ew, deg, cnt, E);
    k_dinv<<<(N + 255) / 256, 256, 0, stream>>>(deg, dinv, N);
    k_scan_a<<<NB, 256, 0, stream>>>(cnt, bsum, N);
    k_scan_b<<<1, 1024, 0, stream>>>(bsum, boff, rowptr, NB, N);
    k_scan_c<<<NB, 256, 0, stream>>>(cnt, boff, rowptr, N);
    k_edge2<<<(E + 255) / 256, 256, 0, stream>>>(srcp, dstp, ew, dinv, rowptr, fill, colb, valb, E);

    k_gemm<<<(N + 63) / 64, 256, 0, stream>>>(x, W1, bufA, N);
    k_agg<<<(N + 3) / 4, 256, 0, stream>>>(bufA, rowptr, colb, valb, dinv, b1, bufB, N);
    k_gemm<<<(N + 63) / 64, 256, 0, stream>>>(bufB, W2, bufA, N);
    k_agg<<<(N + 3) / 4, 256, 0, stream>>>(bufA, rowptr, colb, valb, dinv, b2, bufB, N);

    k_pool<<<G, 256, 0, stream>>>(bufB, gstart, gcnt, gmean);
    k_final<<<G, 128, 0, stream>>>(gmean, gstart, meta, Wm, bm, Wf, bf, (float*)d_out, G);
}

// Round 3
// 670.168 us; speedup vs baseline: 1.5360x; 1.0948x over previous
//
#include <hip/hip_runtime.h>
#include <cstdint>

// ---------------------------------------------------------------------------
// GCN pipeline:
//  packed-u64 deg/cnt atomic -> dinv -> 3-phase scan (rowptr+fill) ->
//  CSR scatter (int2 interleaved) -> GEMM1 -> AGG1 -> GEMM2 -> AGG2 ->
//  mean-pool -> fused head
// ---------------------------------------------------------------------------

#define SCAN_CHUNK 512  // elements per scan block (multiple of 256)
#define FIXSCALE 16777216.0f  // 2^24

__global__ void k_init_small(int* gstart, int* gcnt, int G) {
    int g = blockIdx.x * blockDim.x + threadIdx.x;
    if (g < G) { gstart[g] = 0x7fffffff; gcnt[g] = 0; }
}

__global__ void k_init_nodes(const int* __restrict__ batch,
                             unsigned long long* __restrict__ packed,
                             int* gstart, int* gcnt, int N) {
    int i = blockIdx.x * blockDim.x + threadIdx.x;
    if (i >= N) return;
    packed[i] = 0ull;
    int b = batch[i];
    if (i == 0 || batch[i - 1] != b) gstart[b] = i;  // batch sorted -> unique writer
    atomicAdd(&gcnt[b], 1);
}

// one u64 atomic per edge: low32 = edge count, high32 = sum(ew) in 2^-24 fixed pt
__global__ void k_edge1(const int* __restrict__ dst, const float* __restrict__ ew,
                        unsigned long long* __restrict__ packed, int E) {
    int e = blockIdx.x * blockDim.x + threadIdx.x;
    if (e >= E) return;
    int d = dst[e];
    unsigned int fx = (unsigned int)__float2uint_rn(ew[e] * FIXSCALE);
    atomicAdd(&packed[d], ((unsigned long long)fx << 32) | 1ull);
}

__global__ void k_dinv(const unsigned long long* __restrict__ packed,
                       float* __restrict__ dinv, int* __restrict__ cnt, int N) {
    int i = blockIdx.x * blockDim.x + threadIdx.x;
    if (i >= N) return;
    unsigned long long v = packed[i];
    cnt[i] = (int)(v & 0xffffffffull);
    float deg = 1.0f + (float)(v >> 32) * (1.0f / FIXSCALE);  // self-loop +1
    dinv[i] = rsqrtf(deg);
}

// ---- 3-phase exclusive scan of cnt[N] -> rowptr[N+1] (+ fill seed) --------
__global__ __launch_bounds__(256) void k_scan_a(const int* __restrict__ cnt,
                                                int* __restrict__ bsum, int N) {
    __shared__ int sm[256];
    int base = blockIdx.x * SCAN_CHUNK;
    int end = min(base + SCAN_CHUNK, N);
    int s = 0;
    for (int i = base + threadIdx.x; i < end; i += 256) s += cnt[i];
    sm[threadIdx.x] = s;
    __syncthreads();
    for (int d = 128; d > 0; d >>= 1) {
        if (threadIdx.x < d) sm[threadIdx.x] += sm[threadIdx.x + d];
        __syncthreads();
    }
    if (threadIdx.x == 0) bsum[blockIdx.x] = sm[0];
}

__global__ __launch_bounds__(1024) void k_scan_b(const int* __restrict__ bsum,
                                                 int* __restrict__ boff,
                                                 int* __restrict__ rowptr,
                                                 int NB, int N) {
    __shared__ int sm[1024];
    int tid = threadIdx.x;
    int v = (tid < NB) ? bsum[tid] : 0;
    sm[tid] = v;
    __syncthreads();
    for (int d = 1; d < 1024; d <<= 1) {
        int t = (tid >= d) ? sm[tid - d] : 0;
        __syncthreads();
        sm[tid] += t;
        __syncthreads();
    }
    if (tid < NB) boff[tid] = sm[tid] - v;   // exclusive
    if (tid == NB - 1) rowptr[N] = sm[tid];  // total
}

__global__ __launch_bounds__(256) void k_scan_c(const int* __restrict__ cnt,
                                                const int* __restrict__ boff,
                                                int* __restrict__ rowptr,
                                                int* __restrict__ fill, int N) {
    __shared__ int sm[256];
    int base = blockIdx.x * SCAN_CHUNK;
    int end = min(base + SCAN_CHUNK, N);
    int running = boff[blockIdx.x];
    for (int t0 = base; t0 < end; t0 += 256) {
        int i = t0 + threadIdx.x;
        int v = (i < end) ? cnt[i] : 0;
        sm[threadIdx.x] = v;
        __syncthreads();
        for (int d = 1; d < 256; d <<= 1) {
            int t = (threadIdx.x >= d) ? sm[threadIdx.x - d] : 0;
            __syncthreads();
            sm[threadIdx.x] += t;
            __syncthreads();
        }
        if (i < end) {
            int rp = running + sm[threadIdx.x] - v;
            rowptr[i] = rp;
            fill[i] = rp;  // seed: edge2's atomicAdd returns position directly
        }
        running += sm[255];
        __syncthreads();
    }
}
// ---------------------------------------------------------------------------

__global__ void k_edge2(const int* __restrict__ src, const int* __restrict__ dst,
                        const float* __restrict__ ew, const float* __restrict__ dinv,
                        int* fill, int2* __restrict__ cvb, int E) {
    int e = blockIdx.x * blockDim.x + threadIdx.x;
    if (e >= E) return;
    int s = src[e], d = dst[e];
    int pos = atomicAdd(&fill[d], 1);
    float val = dinv[s] * ew[e] * dinv[d];
    cvb[pos] = make_int2(s, __float_as_int(val));
}

// Y[M,128] = X[M,128] @ W[128,128]   (f32; W via wave-uniform scalar loads)
// block: 256 thr = 4 waves; wave w -> cols [32w,32w+32); lane -> one row.
__global__ __launch_bounds__(256) void k_gemm(const float* __restrict__ X,
                                              const float* __restrict__ W,
                                              float* __restrict__ Y, int M) {
    int tid = threadIdx.x;
    int wid = tid >> 6, lane = tid & 63;
    int row = blockIdx.x * 64 + lane;
    int c0 = __builtin_amdgcn_readfirstlane(wid * 32);  // wave-uniform col base
    if (row >= M) return;
    float acc[32];
#pragma unroll
    for (int c = 0; c < 32; ++c) acc[c] = 0.f;
    const float4* __restrict__ xrow = reinterpret_cast<const float4*>(X + (size_t)row * 128);
#pragma unroll 8
    for (int k4 = 0; k4 < 32; ++k4) {
        float4 xv = xrow[k4];
#pragma unroll
        for (int j = 0; j < 4; ++j) {
            float xk = (j == 0) ? xv.x : (j == 1) ? xv.y : (j == 2) ? xv.z : xv.w;
            const float* __restrict__ wrow = W + (size_t)(k4 * 4 + j) * 128 + c0;
#pragma unroll
            for (int c = 0; c < 32; ++c) acc[c] = fmaf(xk, wrow[c], acc[c]);
        }
    }
    float4* yrow = reinterpret_cast<float4*>(Y + (size_t)row * 128 + c0);
#pragma unroll
    for (int q = 0; q < 8; ++q)
        yrow[q] = make_float4(acc[4 * q], acc[4 * q + 1], acc[4 * q + 2], acc[4 * q + 3]);
}

// Out[d] = relu( sum_e val[e]*Hin[col[e]] + dinv[d]^2*Hin[d] + bias )
// one wave per node; lane holds 2 features (float2).
__global__ __launch_bounds__(256) void k_agg(const float* __restrict__ Hin,
                                             const int* __restrict__ rowptr,
                                             const int2* __restrict__ cvb,
                                             const float* __restrict__ dinv,
                                             const float* __restrict__ bias,
                                             float* __restrict__ Out, int N) {
    int lane = threadIdx.x & 63;
    int node = blockIdx.x * 4 + (threadIdx.x >> 6);
    if (node >= N) return;
    const float2* __restrict__ H2 = reinterpret_cast<const float2*>(Hin);
    int beg = rowptr[node], end = rowptr[node + 1];
    float di = dinv[node];
    float2 hs = H2[(size_t)node * 64 + lane];
    float sn = di * di;
    float a0 = sn * hs.x, a1 = sn * hs.y;
    int n = end - beg;
    for (int base = 0; base < n; base += 64) {
        int m = min(64, n - base);
        int cl = 0; float vl = 0.f;
        if (base + lane < n) {
            int2 cv = cvb[beg + base + lane];
            cl = cv.x;
            vl = __int_as_float(cv.y);
        }
        for (int j0 = 0; j0 < m; j0 += 4) {
#pragma unroll
            for (int jj = 0; jj < 4; ++jj) {
                int j = j0 + jj;
                if (j < m) {
                    int sIdx = __shfl(cl, j);
                    float v = __shfl(vl, j);
                    float2 h = H2[(size_t)sIdx * 64 + lane];
                    a0 = fmaf(v, h.x, a0);
                    a1 = fmaf(v, h.y, a1);
                }
            }
        }
    }
    float2 bv = reinterpret_cast<const float2*>(bias)[lane];
    a0 = fmaxf(a0 + bv.x, 0.f);
    a1 = fmaxf(a1 + bv.y, 0.f);
    reinterpret_cast<float2*>(Out)[(size_t)node * 64 + lane] = make_float2(a0, a1);
}

// mean pool: batch sorted -> graph g is rows [gstart[g], gstart[g]+gcnt[g])
__global__ __launch_bounds__(256) void k_pool(const float* __restrict__ Hfin,
                                              const int* __restrict__ gstart,
                                              const int* __restrict__ gcnt,
                                              float* __restrict__ gmean) {
    int g = blockIdx.x;
    int tid = threadIdx.x;
    int c = tid & 127, half = tid >> 7;
    __shared__ float red[256];
    int cntg = gcnt[g];
    int b = gstart[g];
    float s = 0.f;
    for (int i = half; i < cntg; i += 2) s += Hfin[(size_t)(b + i) * 128 + c];
    red[tid] = s;
    __syncthreads();
    if (half == 0) {
        float tot = red[c] + red[c + 128];
        gmean[g * 128 + c] = tot / fmaxf((float)cntg, 1.f);
    }
}

// head: md = relu(metadata[first%G] @ Wm + bm); out = [pooled, md] @ Wf + bf
__global__ __launch_bounds__(128) void k_final(const float* __restrict__ gmean,
                                               const int* __restrict__ gstart,
                                               const float* __restrict__ meta,
                                               const float* __restrict__ Wm,
                                               const float* __restrict__ bm,
                                               const float* __restrict__ Wf,
                                               const float* __restrict__ bf,
                                               float* __restrict__ out, int G) {
    int g = blockIdx.x;
    int c = threadIdx.x;  // 128 threads
    __shared__ float red[128];
    float pooled = gmean[g * 128 + c];
    int fn = gstart[g];          // INT_MAX for empty graph (matches segment_min identity)
    int idx = fn % G;            // metadata.shape[0] == G
    float m = bm[c];
#pragma unroll
    for (int k = 0; k < 30; ++k) m = fmaf(meta[idx * 30 + k], Wm[k * 128 + c], m);
    m = fmaxf(m, 0.f);
    float part = pooled * Wf[c] + m * Wf[128 + c];
    red[c] = part;
    __syncthreads();
    for (int st = 64; st > 0; st >>= 1) {
        if (c < st) red[c] += red[c + st];
        __syncthreads();
    }
    if (c == 0) out[g] = red[0] + bf[0];
}

extern "C" void kernel_launch(void* const* d_in, const int* in_sizes, int n_in,
                              void* d_out, int out_size, void* d_ws, size_t ws_size,
                              hipStream_t stream) {
    const float* x     = (const float*)d_in[0];
    const int*   ei    = (const int*)d_in[1];
    const float* ew    = (const float*)d_in[2];
    const int*   batch = (const int*)d_in[3];
    const float* meta  = (const float*)d_in[4];
    const float* W1    = (const float*)d_in[5];
    const float* b1    = (const float*)d_in[6];
    const float* W2    = (const float*)d_in[7];
    const float* b2    = (const float*)d_in[8];
    const float* Wm    = (const float*)d_in[9];
    const float* bm    = (const float*)d_in[10];
    const float* Wf    = (const float*)d_in[11];
    const float* bf    = (const float*)d_in[12];

    int N = in_sizes[0] / 128;
    int E = in_sizes[2];
    int G = in_sizes[4] / 30;
    const int* srcp = ei;
    const int* dstp = ei + E;

    char* p = (char*)d_ws;
    auto alloc = [&](size_t bytes) -> void* {
        void* r = p;
        p += (bytes + 255) & ~(size_t)255;
        return r;
    };
    unsigned long long* packed = (unsigned long long*)alloc((size_t)N * 8);
    float* dinv   = (float*)alloc((size_t)N * 4);
    int*   cnt    = (int*)alloc((size_t)N * 4);
    int*   fill   = (int*)alloc((size_t)N * 4);
    int*   rowptr = (int*)alloc((size_t)(N + 1) * 4);
    int2*  cvb    = (int2*)alloc((size_t)E * 8);
    float* bufA   = (float*)alloc((size_t)N * 128 * 4);
    float* bufB   = (float*)alloc((size_t)N * 128 * 4);
    float* gmean  = (float*)alloc((size_t)G * 128 * 4);
    int*   gstart = (int*)alloc((size_t)G * 4);
    int*   gcnt   = (int*)alloc((size_t)G * 4);
    int NB = (N + SCAN_CHUNK - 1) / SCAN_CHUNK;
    int*   bsum   = (int*)alloc((size_t)NB * 4);
    int*   boff   = (int*)alloc((size_t)NB * 4);

    k_init_small<<<(G + 255) / 256, 256, 0, stream>>>(gstart, gcnt, G);
    k_init_nodes<<<(N + 255) / 256, 256, 0, stream>>>(batch, packed, gstart, gcnt, N);
    k_edge1<<<(E + 255) / 256, 256, 0, stream>>>(dstp, ew, packed, E);
    k_dinv<<<(N + 255) / 256, 256, 0, stream>>>(packed, dinv, cnt, N);
    k_scan_a<<<NB, 256, 0, stream>>>(cnt, bsum, N);
    k_scan_b<<<1, 1024, 0, stream>>>(bsum, boff, rowptr, NB, N);
    k_scan_c<<<NB, 256, 0, stream>>>(cnt, boff, rowptr, fill, N);
    k_edge2<<<(E + 255) / 256, 256, 0, stream>>>(srcp, dstp, ew, dinv, fill, cvb, E);

    k_gemm<<<(N + 63) / 64, 256, 0, stream>>>(x, W1, bufA, N);
    k_agg<<<(N + 3) / 4, 256, 0, stream>>>(bufA, rowptr, cvb, dinv, b1, bufB, N);
    k_gemm<<<(N + 63) / 64, 256, 0, stream>>>(bufB, W2, bufA, N);
    k_agg<<<(N + 3) / 4, 256, 0, stream>>>(bufA, rowptr, cvb, dinv, b2, bufB, N);

    k_pool<<<G, 256, 0, stream>>>(bufB, gstart, gcnt, gmean);
    k_final<<<G, 128, 0, stream>>>(gmean, gstart, meta, Wm, bm, Wf, bf, (float*)d_out, G);
}